// Round 15
// baseline (70.668 us; speedup 1.0000x reference)
//
#include <hip/hip_runtime.h>
#include <hip/hip_bf16.h>
#include <math.h>

#define B_ 512
#define C_ 100000
#define D_ 128
#define SC 32                          // proxy cols per step
#define NITER 6                        // steps per block
#define GX 521                         // ceil((C_/SC)=3125 / NITER)
#define NPAD (GX * NITER * SC - C_)    // 32 zero-padded cols
#define LOG2E 1.4426950408889634f
#define K2S (2.0f * LOG2E)             // score_log2 = dot*K2S + K18S
#define K18S (-18.0f * LOG2E)

typedef __attribute__((ext_vector_type(8))) short short8;  // 8 bf16 (MFMA A/B frag)
typedef __attribute__((ext_vector_type(4))) float f32x4;   // MFMA C/D frag

#if defined(__has_builtin)
#if __has_builtin(__builtin_amdgcn_exp2f)
#define EXP2F(x) __builtin_amdgcn_exp2f(x)
#endif
#endif
#ifndef EXP2F
#define EXP2F(x) __expf(0.69314718055994531f * (x))
#endif

// async global -> LDS, 16 B per lane; LDS dest = wave-uniform base, HW adds lane*16
__device__ __forceinline__ void gll16(const void* g, void* l) {
  __builtin_amdgcn_global_load_lds(
      (const __attribute__((address_space(1))) void*)g,
      (__attribute__((address_space(3))) void*)l, 16, 0, 0);
}

// --- main kernel --------------------------------------------------------------
// grid (GX, 2), 512 thr (8 waves), 48 KB LDS, <=128 VGPR -> 2 blocks/CU.
// Block (gx, gy): proxy cols [gx*192, +192) in 6 steps of 32; batch rows
// [gy*256, +256), wave w owns rows gy*256 + w*32 .. +31 (a[2][4] frags).
// Per step: STAGE(next f32, gll16) ; COMPUTE(cur B) ; sync ; CVT(next) ; sync.
__global__ __launch_bounds__(512, 4) void pnca_main_kernel(
    const float* __restrict__ praw, const float* __restrict__ batch,
    float* __restrict__ pt)
{
  __shared__ __align__(16) float         fbuf[2][SC * D_];     // 2 x 16 KB f32
  __shared__ __align__(16) unsigned char bbuf[2][SC * 256];    // 2 x 8 KB bf16 (swizzled)

  const int tid  = threadIdx.x;
  const int lane = tid & 63;
  const int w    = tid >> 6;
  const int ll   = lane & 15;
  const int lq   = lane >> 4;
  const int gx   = blockIdx.x;
  const int st0  = gx * NITER;
  const int rb   = blockIdx.y * 256;

  // A fragments: wave w's 32 rows, raw f32 from L2-hot batch, normalize, pack
  short8 a[2][4];
#pragma unroll
  for (int m = 0; m < 2; ++m) {
    float4 t0[4], t1[4];
    float ssm = 0.f;
#pragma unroll
    for (int ks = 0; ks < 4; ++ks) {
      const float* rp = batch + (size_t)(rb + w * 32 + m * 16 + ll) * D_ + ks * 32 + lq * 8;
      t0[ks] = *(const float4*)rp;
      t1[ks] = *(const float4*)(rp + 4);
      ssm += t0[ks].x * t0[ks].x + t0[ks].y * t0[ks].y + t0[ks].z * t0[ks].z + t0[ks].w * t0[ks].w
           + t1[ks].x * t1[ks].x + t1[ks].y * t1[ks].y + t1[ks].z * t1[ks].z + t1[ks].w * t1[ks].w;
    }
    ssm += __shfl_xor(ssm, 16);
    ssm += __shfl_xor(ssm, 32);
    float sc = 3.f / fmaxf(sqrtf(ssm), 1e-12f);
#pragma unroll
    for (int ks = 0; ks < 4; ++ks) {
      union { short8 s8; __hip_bfloat162 h[4]; } u;
      u.h[0] = __float22bfloat162_rn(make_float2(t0[ks].x * sc, t0[ks].y * sc));
      u.h[1] = __float22bfloat162_rn(make_float2(t0[ks].z * sc, t0[ks].w * sc));
      u.h[2] = __float22bfloat162_rn(make_float2(t1[ks].x * sc, t1[ks].y * sc));
      u.h[3] = __float22bfloat162_rn(make_float2(t1[ks].z * sc, t1[ks].w * sc));
      a[m][ks] = u.s8;
    }
  }

  float part[2][4];
#pragma unroll
  for (int m = 0; m < 2; ++m)
#pragma unroll
    for (int r = 0; r < 4; ++r) part[m][r] = 0.f;

  // stage step st: 32 cols x 512 B raw f32, linear, 2 gll16/thread
  auto STAGE = [&](int st, int pp) {
    const unsigned char* gb = (const unsigned char*)praw;
#pragma unroll
    for (int k = 0; k < 2; ++k) {
      int slot = k * 512 + tid;                // 16B-unit index in the tile
      int gr   = st * SC + (slot >> 5);        // proxy row
      if (gr >= C_) gr = C_ - 1;
      gll16(gb + ((size_t)gr * 32 + (slot & 31)) * 16,
            (unsigned char*)fbuf[pp] + (size_t)(k * 512 + w * 64) * 16);
    }
  };

  // cooperative convert: 16 threads/col, thread j owns dims 8j..8j+7 (one unit)
  auto CVT = [&](int st, int pp) {
    const int c = tid >> 4, j = tid & 15;
    const float* Fb = fbuf[pp] + (size_t)c * D_ + j * 8;
    float4 v0 = *(const float4*)Fb;
    float4 v1 = *(const float4*)(Fb + 4);
    float ss = v0.x * v0.x + v0.y * v0.y + v0.z * v0.z + v0.w * v0.w
             + v1.x * v1.x + v1.y * v1.y + v1.z * v1.z + v1.w * v1.w;
    ss += __shfl_xor(ss, 1);
    ss += __shfl_xor(ss, 2);
    ss += __shfl_xor(ss, 4);
    ss += __shfl_xor(ss, 8);
    float sc = (st * SC + c < C_) ? 3.0f * __frsqrt_rn(fmaxf(ss, 1e-24f)) : 0.0f;
    union { short8 s8; __hip_bfloat162 h[4]; } u;
    u.h[0] = __float22bfloat162_rn(make_float2(v0.x * sc, v0.y * sc));
    u.h[1] = __float22bfloat162_rn(make_float2(v0.z * sc, v0.w * sc));
    u.h[2] = __float22bfloat162_rn(make_float2(v1.x * sc, v1.y * sc));
    u.h[3] = __float22bfloat162_rn(make_float2(v1.z * sc, v1.w * sc));
    int pu = j ^ (c & 7);                      // XOR-swizzled 16B unit
    *(short8*)(bbuf[pp] + (size_t)c * 256 + pu * 16) = u.s8;
  };

  auto COMPUTE = [&](int pp) {
    const unsigned char* Bb = bbuf[pp];
#pragma unroll
    for (int g = 0; g < 2; ++g) {
      const int cg = g * 16 + ll;
      short8 bfr[4];
#pragma unroll
      for (int ks = 0; ks < 4; ++ks)
        bfr[ks] = *(const short8*)(Bb + (size_t)cg * 256 + ((ks * 4 + lq) ^ (cg & 7)) * 16);
      f32x4 acc0 = (f32x4){0.f, 0.f, 0.f, 0.f};
      f32x4 acc1 = (f32x4){0.f, 0.f, 0.f, 0.f};
#pragma unroll
      for (int ks = 0; ks < 4; ++ks) {
        acc0 = __builtin_amdgcn_mfma_f32_16x16x32_bf16(a[0][ks], bfr[ks], acc0, 0, 0, 0);
        acc1 = __builtin_amdgcn_mfma_f32_16x16x32_bf16(a[1][ks], bfr[ks], acc1, 0, 0, 0);
      }
#pragma unroll
      for (int r = 0; r < 4; ++r) {
        part[0][r] += EXP2F(fmaf(acc0[r], K2S, K18S));
        part[1][r] += EXP2F(fmaf(acc1[r], K2S, K18S));
      }
    }
  };

  // prologue
  STAGE(st0, 0);
  __syncthreads();
  CVT(st0, 0);
  __syncthreads();

  int p = 0;
#pragma unroll
  for (int it = 0; it < NITER; ++it) {
    const bool hn = (it + 1 < NITER);
    if (hn) STAGE(st0 + it + 1, p ^ 1);   // async, flies under COMPUTE
    COMPUTE(p);
    if (hn) {
      __syncthreads();                     // drains vmcnt: F[p^1] staged
      CVT(st0 + it + 1, p ^ 1);
      __syncthreads();                     // B[p^1] ready
    }
    p ^= 1;
  }

  // epilogue: 16-lane reduce, one pt write per (block,row)
#pragma unroll
  for (int m = 0; m < 2; ++m)
#pragma unroll
    for (int r = 0; r < 4; ++r) {
      float v = part[m][r];
      v += __shfl_xor(v, 1);
      v += __shfl_xor(v, 2);
      v += __shfl_xor(v, 4);
      v += __shfl_xor(v, 8);
      if (ll == 0)
        pt[(size_t)gx * B_ + rb + w * 32 + m * 16 + lq * 4 + r] = v;
    }
}

// --- kernel 2: per-row combine + positive distance + loss ---------------------
__global__ __launch_bounds__(256) void finalize_rows_kernel(
    const float* __restrict__ praw, const float* __restrict__ batch,
    const int* __restrict__ labels, const float* __restrict__ pt,
    float* __restrict__ lossb)
{
  int lane = threadIdx.x & 63, wv = threadIdx.x >> 6;
  int row = blockIdx.x * 4 + wv;             // grid=128 -> 512 rows
  int lab = labels[row];
  float2 pv = *(const float2*)(praw + (size_t)lab * D_ + lane * 2);
  float2 xv = *(const float2*)(batch + (size_t)row * D_ + lane * 2);
  float ssp = pv.x * pv.x + pv.y * pv.y;
  float ssx = xv.x * xv.x + xv.y * xv.y;
  float dp  = xv.x * pv.x + xv.y * pv.y;
#pragma unroll
  for (int off = 32; off; off >>= 1) {
    ssp += __shfl_xor(ssp, off);
    ssx += __shfl_xor(ssx, off);
    dp  += __shfl_xor(dp, off);
  }
  float pd = 18.f - 18.f * dp / (fmaxf(sqrtf(ssx), 1e-12f) * fmaxf(sqrtf(ssp), 1e-12f));
  float s = 0.f;
  for (int gg = lane; gg < GX; gg += 64) s += pt[(size_t)gg * B_ + row];
#pragma unroll
  for (int off = 32; off; off >>= 1) s += __shfl_xor(s, off);
  if (lane == 0) {
    const float tail = (float)NPAD * EXP2F(K18S);   // zero-padded cols' exact sum
    lossb[row] = pd + logf(s - __expf(-pd) - tail);
  }
}

// --- kernel 3: mean over 512 rows ---------------------------------------------
__global__ __launch_bounds__(512) void reduce_mean_kernel(
    const float* __restrict__ lossb, float* __restrict__ out)
{
  int t = threadIdx.x;
  float v = lossb[t];
#pragma unroll
  for (int off = 1; off < 64; off <<= 1) v += __shfl_xor(v, off);
  __shared__ float red[8];
  if ((t & 63) == 0) red[t >> 6] = v;
  __syncthreads();
  if (t == 0) {
    float tot = 0.f;
    for (int i = 0; i < 8; ++i) tot += red[i];
    out[0] = tot / (float)B_;
  }
}

extern "C" void kernel_launch(void* const* d_in, const int* in_sizes, int n_in,
                              void* d_out, int out_size, void* d_ws, size_t ws_size,
                              hipStream_t stream)
{
  const float* batch   = (const float*)d_in[0];
  const int*   labels  = (const int*)d_in[1];
  const float* proxies = (const float*)d_in[2];
  float* out = (float*)d_out;

  unsigned char* ws = (unsigned char*)d_ws;
  float* pt    = (float*)ws;                               // 521*512*4 ~= 1.07 MB
  float* lossb = (float*)(ws + (size_t)GX * B_ * 4);       // 2 KB

  dim3 grid(GX, 2);
  pnca_main_kernel<<<grid, 512, 0, stream>>>(proxies, batch, pt);
  finalize_rows_kernel<<<B_ / 4, 256, 0, stream>>>(proxies, batch, labels, pt, lossb);
  reduce_mean_kernel<<<1, 512, 0, stream>>>(lossb, out);
}

// Round 16
// 67.704 us; speedup vs baseline: 1.0438x; 1.0438x over previous
//
#include <hip/hip_runtime.h>
#include <hip/hip_bf16.h>
#include <math.h>

#define B_ 512
#define C_ 100000
#define D_ 128
#define SC 32                          // proxy cols per step
#define NITER 6                        // steps per block
#define GX 521                         // ceil((C_/SC)=3125 / NITER)
#define NPAD (GX * NITER * SC - C_)    // 32 zero-padded cols
#define LOG2E 1.4426950408889634f
#define K2S (2.0f * LOG2E)             // score_log2 = dot*K2S + K18S
#define K18S (-18.0f * LOG2E)

typedef __attribute__((ext_vector_type(8))) short short8;  // 8 bf16 (MFMA A/B frag)
typedef __attribute__((ext_vector_type(4))) float f32x4;   // MFMA C/D frag

#if defined(__has_builtin)
#if __has_builtin(__builtin_amdgcn_exp2f)
#define EXP2F(x) __builtin_amdgcn_exp2f(x)
#endif
#endif
#ifndef EXP2F
#define EXP2F(x) __expf(0.69314718055994531f * (x))
#endif

// async global -> LDS, 16 B per lane; LDS dest = wave-uniform base, HW adds lane*16
__device__ __forceinline__ void gll16(const void* g, void* l) {
  __builtin_amdgcn_global_load_lds(
      (const __attribute__((address_space(1))) void*)g,
      (__attribute__((address_space(3))) void*)l, 16, 0, 0);
}

// --- main kernel --------------------------------------------------------------
// grid (GX, 2), 512 thr (8 waves), 48 KB LDS. __launch_bounds__(512,2): R13/R14's
// proven no-spill setting (VGPR ~80-100 <= 128 -> HW gives 4 waves/SIMD anyway
// = 2 blocks/CU; R15's (512,4) forced a 64-VGPR cap -> 120 MB scratch spill).
// Block (gx, gy): proxy cols [gx*192, +192) in 6 steps of 32; batch rows
// [gy*256, +256), wave w owns rows gy*256 + w*32 .. +31 (a[2][4] frags).
// Per step: STAGE(next f32, gll16) ; COMPUTE(cur B) ; sync ; CVT(next) ; sync.
__global__ __launch_bounds__(512, 2) void pnca_main_kernel(
    const float* __restrict__ praw, const float* __restrict__ batch,
    float* __restrict__ pt)
{
  __shared__ __align__(16) float         fbuf[2][SC * D_];     // 2 x 16 KB f32
  __shared__ __align__(16) unsigned char bbuf[2][SC * 256];    // 2 x 8 KB bf16 (swizzled)

  const int tid  = threadIdx.x;
  const int lane = tid & 63;
  const int w    = tid >> 6;
  const int ll   = lane & 15;
  const int lq   = lane >> 4;
  const int gx   = blockIdx.x;
  const int st0  = gx * NITER;
  const int rb   = blockIdx.y * 256;

  // A fragments: wave w's 32 rows, raw f32 from L2-hot batch, normalize, pack
  short8 a[2][4];
#pragma unroll
  for (int m = 0; m < 2; ++m) {
    float4 t0[4], t1[4];
    float ssm = 0.f;
#pragma unroll
    for (int ks = 0; ks < 4; ++ks) {
      const float* rp = batch + (size_t)(rb + w * 32 + m * 16 + ll) * D_ + ks * 32 + lq * 8;
      t0[ks] = *(const float4*)rp;
      t1[ks] = *(const float4*)(rp + 4);
      ssm += t0[ks].x * t0[ks].x + t0[ks].y * t0[ks].y + t0[ks].z * t0[ks].z + t0[ks].w * t0[ks].w
           + t1[ks].x * t1[ks].x + t1[ks].y * t1[ks].y + t1[ks].z * t1[ks].z + t1[ks].w * t1[ks].w;
    }
    ssm += __shfl_xor(ssm, 16);
    ssm += __shfl_xor(ssm, 32);
    float sc = 3.f / fmaxf(sqrtf(ssm), 1e-12f);
#pragma unroll
    for (int ks = 0; ks < 4; ++ks) {
      union { short8 s8; __hip_bfloat162 h[4]; } u;
      u.h[0] = __float22bfloat162_rn(make_float2(t0[ks].x * sc, t0[ks].y * sc));
      u.h[1] = __float22bfloat162_rn(make_float2(t0[ks].z * sc, t0[ks].w * sc));
      u.h[2] = __float22bfloat162_rn(make_float2(t1[ks].x * sc, t1[ks].y * sc));
      u.h[3] = __float22bfloat162_rn(make_float2(t1[ks].z * sc, t1[ks].w * sc));
      a[m][ks] = u.s8;
    }
  }

  float part[2][4];
#pragma unroll
  for (int m = 0; m < 2; ++m)
#pragma unroll
    for (int r = 0; r < 4; ++r) part[m][r] = 0.f;

  // stage step st: 32 cols x 512 B raw f32, linear, 2 gll16/thread
  auto STAGE = [&](int st, int pp) {
    const unsigned char* gb = (const unsigned char*)praw;
#pragma unroll
    for (int k = 0; k < 2; ++k) {
      int slot = k * 512 + tid;                // 16B-unit index in the tile
      int gr   = st * SC + (slot >> 5);        // proxy row
      if (gr >= C_) gr = C_ - 1;
      gll16(gb + ((size_t)gr * 32 + (slot & 31)) * 16,
            (unsigned char*)fbuf[pp] + (size_t)(k * 512 + w * 64) * 16);
    }
  };

  // cooperative convert: 16 threads/col, thread j owns dims 8j..8j+7 (one unit)
  auto CVT = [&](int st, int pp) {
    const int c = tid >> 4, j = tid & 15;
    const float* Fb = fbuf[pp] + (size_t)c * D_ + j * 8;
    float4 v0 = *(const float4*)Fb;
    float4 v1 = *(const float4*)(Fb + 4);
    float ss = v0.x * v0.x + v0.y * v0.y + v0.z * v0.z + v0.w * v0.w
             + v1.x * v1.x + v1.y * v1.y + v1.z * v1.z + v1.w * v1.w;
    ss += __shfl_xor(ss, 1);
    ss += __shfl_xor(ss, 2);
    ss += __shfl_xor(ss, 4);
    ss += __shfl_xor(ss, 8);
    float sc = (st * SC + c < C_) ? 3.0f * __frsqrt_rn(fmaxf(ss, 1e-24f)) : 0.0f;
    union { short8 s8; __hip_bfloat162 h[4]; } u;
    u.h[0] = __float22bfloat162_rn(make_float2(v0.x * sc, v0.y * sc));
    u.h[1] = __float22bfloat162_rn(make_float2(v0.z * sc, v0.w * sc));
    u.h[2] = __float22bfloat162_rn(make_float2(v1.x * sc, v1.y * sc));
    u.h[3] = __float22bfloat162_rn(make_float2(v1.z * sc, v1.w * sc));
    int pu = j ^ (c & 7);                      // XOR-swizzled 16B unit
    *(short8*)(bbuf[pp] + (size_t)c * 256 + pu * 16) = u.s8;
  };

  auto COMPUTE = [&](int pp) {
    const unsigned char* Bb = bbuf[pp];
#pragma unroll
    for (int g = 0; g < 2; ++g) {
      const int cg = g * 16 + ll;
      short8 bfr[4];
#pragma unroll
      for (int ks = 0; ks < 4; ++ks)
        bfr[ks] = *(const short8*)(Bb + (size_t)cg * 256 + ((ks * 4 + lq) ^ (cg & 7)) * 16);
      f32x4 acc0 = (f32x4){0.f, 0.f, 0.f, 0.f};
      f32x4 acc1 = (f32x4){0.f, 0.f, 0.f, 0.f};
#pragma unroll
      for (int ks = 0; ks < 4; ++ks) {
        acc0 = __builtin_amdgcn_mfma_f32_16x16x32_bf16(a[0][ks], bfr[ks], acc0, 0, 0, 0);
        acc1 = __builtin_amdgcn_mfma_f32_16x16x32_bf16(a[1][ks], bfr[ks], acc1, 0, 0, 0);
      }
#pragma unroll
      for (int r = 0; r < 4; ++r) {
        part[0][r] += EXP2F(fmaf(acc0[r], K2S, K18S));
        part[1][r] += EXP2F(fmaf(acc1[r], K2S, K18S));
      }
    }
  };

  // prologue
  STAGE(st0, 0);
  __syncthreads();
  CVT(st0, 0);
  __syncthreads();

  int p = 0;
#pragma unroll
  for (int it = 0; it < NITER; ++it) {
    const bool hn = (it + 1 < NITER);
    if (hn) STAGE(st0 + it + 1, p ^ 1);   // async, flies under COMPUTE
    COMPUTE(p);
    if (hn) {
      __syncthreads();                     // drains vmcnt: F[p^1] staged
      CVT(st0 + it + 1, p ^ 1);
      __syncthreads();                     // B[p^1] ready
    }
    p ^= 1;
  }

  // epilogue: 16-lane reduce, one pt write per (block,row)
#pragma unroll
  for (int m = 0; m < 2; ++m)
#pragma unroll
    for (int r = 0; r < 4; ++r) {
      float v = part[m][r];
      v += __shfl_xor(v, 1);
      v += __shfl_xor(v, 2);
      v += __shfl_xor(v, 4);
      v += __shfl_xor(v, 8);
      if (ll == 0)
        pt[(size_t)gx * B_ + rb + w * 32 + m * 16 + lq * 4 + r] = v;
    }
}

// --- kernel 2: per-row combine + positive distance + loss ---------------------
__global__ __launch_bounds__(256) void finalize_rows_kernel(
    const float* __restrict__ praw, const float* __restrict__ batch,
    const int* __restrict__ labels, const float* __restrict__ pt,
    float* __restrict__ lossb)
{
  int lane = threadIdx.x & 63, wv = threadIdx.x >> 6;
  int row = blockIdx.x * 4 + wv;             // grid=128 -> 512 rows
  int lab = labels[row];
  float2 pv = *(const float2*)(praw + (size_t)lab * D_ + lane * 2);
  float2 xv = *(const float2*)(batch + (size_t)row * D_ + lane * 2);
  float ssp = pv.x * pv.x + pv.y * pv.y;
  float ssx = xv.x * xv.x + xv.y * xv.y;
  float dp  = xv.x * pv.x + xv.y * pv.y;
#pragma unroll
  for (int off = 32; off; off >>= 1) {
    ssp += __shfl_xor(ssp, off);
    ssx += __shfl_xor(ssx, off);
    dp  += __shfl_xor(dp, off);
  }
  float pd = 18.f - 18.f * dp / (fmaxf(sqrtf(ssx), 1e-12f) * fmaxf(sqrtf(ssp), 1e-12f));
  float s = 0.f;
  for (int gg = lane; gg < GX; gg += 64) s += pt[(size_t)gg * B_ + row];
#pragma unroll
  for (int off = 32; off; off >>= 1) s += __shfl_xor(s, off);
  if (lane == 0) {
    const float tail = (float)NPAD * EXP2F(K18S);   // zero-padded cols' exact sum
    lossb[row] = pd + logf(s - __expf(-pd) - tail);
  }
}

// --- kernel 3: mean over 512 rows ---------------------------------------------
__global__ __launch_bounds__(512) void reduce_mean_kernel(
    const float* __restrict__ lossb, float* __restrict__ out)
{
  int t = threadIdx.x;
  float v = lossb[t];
#pragma unroll
  for (int off = 1; off < 64; off <<= 1) v += __shfl_xor(v, off);
  __shared__ float red[8];
  if ((t & 63) == 0) red[t >> 6] = v;
  __syncthreads();
  if (t == 0) {
    float tot = 0.f;
    for (int i = 0; i < 8; ++i) tot += red[i];
    out[0] = tot / (float)B_;
  }
}

extern "C" void kernel_launch(void* const* d_in, const int* in_sizes, int n_in,
                              void* d_out, int out_size, void* d_ws, size_t ws_size,
                              hipStream_t stream)
{
  const float* batch   = (const float*)d_in[0];
  const int*   labels  = (const int*)d_in[1];
  const float* proxies = (const float*)d_in[2];
  float* out = (float*)d_out;

  unsigned char* ws = (unsigned char*)d_ws;
  float* pt    = (float*)ws;                               // 521*512*4 ~= 1.07 MB
  float* lossb = (float*)(ws + (size_t)GX * B_ * 4);       // 2 KB

  dim3 grid(GX, 2);
  pnca_main_kernel<<<grid, 512, 0, stream>>>(proxies, batch, pt);
  finalize_rows_kernel<<<B_ / 4, 256, 0, stream>>>(proxies, batch, labels, pt, lossb);
  reduce_mean_kernel<<<1, 512, 0, stream>>>(lossb, out);
}

// Round 17
// 49.526 us; speedup vs baseline: 1.4269x; 1.3671x over previous
//
#include <hip/hip_runtime.h>
#include <hip/hip_bf16.h>
#include <math.h>

#define B_ 512
#define C_ 100000
#define D_ 128
#define CT 128                       // proxy cols per step tile
#define NT 782                       // col tiles
#define NSTEP (NT * 2)               // 1564 (tile, row-half) steps
#define MAIN_GRID 512                // persistent; half = s&1 constant per block
#define NPAD (NT * CT - C_)          // 96 zero cols in tile 781
#define LOG2E 1.4426950408889634f
#define K2S (2.0f * LOG2E)           // score_log2 = dot*K2S + K18S
#define K18S (-18.0f * LOG2E)

typedef __attribute__((ext_vector_type(8))) short short8;  // 8 bf16 (MFMA A/B frag)
typedef __attribute__((ext_vector_type(4))) float f32x4;   // MFMA C/D frag

#if defined(__has_builtin)
#if __has_builtin(__builtin_amdgcn_exp2f)
#define EXP2F(x) __builtin_amdgcn_exp2f(x)
#endif
#endif
#ifndef EXP2F
#define EXP2F(x) __expf(0.69314718055994531f * (x))
#endif

// --- main kernel: T14 async-reg staging, no f32 LDS, 1 barrier/step -----------
// 512 persistent blocks x 8 waves, 64 KB LDS (2 x 32 KB bf16 dbuf) -> 2/CU.
// Block b: steps s = b, b+512, ... ; half=s&1 const; wave w rows half*256+w*32.
// Per step: issue next tile's f32 into regs (8 indep float4/thread) ->
// COMPUTE(bbuf[p]) hides the HBM latency -> CVT regs->bbuf[p^1] -> barrier.
__global__ __launch_bounds__(512, 2) void pnca_main_kernel(
    const float* __restrict__ praw, const float* __restrict__ batch,
    float* __restrict__ pt)
{
  __shared__ __align__(16) unsigned char bbuf[2][CT * 256];  // 2 x 32 KB swizzled bf16

  const int tid  = threadIdx.x;
  const int lane = tid & 63;
  const int w    = tid >> 6;
  const int ll   = lane & 15;
  const int lq   = lane >> 4;
  const int c    = tid >> 2;        // staging col 0..127 (4 threads/col)
  const int j    = tid & 3;         // quarter of the 128-dim row

  int s = blockIdx.x;
  const int half  = s & 1;
  const int rbase = half * 256 + w * 32;

  // A fragments: wave's 32 batch rows, raw f32 (L2-hot), normalize, pack bf16
  short8 a[2][4];
#pragma unroll
  for (int m = 0; m < 2; ++m) {
    float4 t0[4], t1[4];
    float ssm = 0.f;
#pragma unroll
    for (int ks = 0; ks < 4; ++ks) {
      const float* rp = batch + (size_t)(rbase + m * 16 + ll) * D_ + ks * 32 + lq * 8;
      t0[ks] = *(const float4*)rp;
      t1[ks] = *(const float4*)(rp + 4);
      ssm += t0[ks].x * t0[ks].x + t0[ks].y * t0[ks].y + t0[ks].z * t0[ks].z + t0[ks].w * t0[ks].w
           + t1[ks].x * t1[ks].x + t1[ks].y * t1[ks].y + t1[ks].z * t1[ks].z + t1[ks].w * t1[ks].w;
    }
    ssm += __shfl_xor(ssm, 16);
    ssm += __shfl_xor(ssm, 32);
    float sc = 3.f / fmaxf(sqrtf(ssm), 1e-12f);
#pragma unroll
    for (int ks = 0; ks < 4; ++ks) {
      union { short8 s8; __hip_bfloat162 h[4]; } u;
      u.h[0] = __float22bfloat162_rn(make_float2(t0[ks].x * sc, t0[ks].y * sc));
      u.h[1] = __float22bfloat162_rn(make_float2(t0[ks].z * sc, t0[ks].w * sc));
      u.h[2] = __float22bfloat162_rn(make_float2(t1[ks].x * sc, t1[ks].y * sc));
      u.h[3] = __float22bfloat162_rn(make_float2(t1[ks].z * sc, t1[ks].w * sc));
      a[m][ks] = u.s8;
    }
  }

  float part[2][4];
#pragma unroll
  for (int m = 0; m < 2; ++m)
#pragma unroll
    for (int r = 0; r < 4; ++r) part[m][r] = 0.f;

  float4 vst[8];   // staging registers: this thread's 32 dims of col c (32 VGPR)

  // issue the 8 independent f32 loads for step s_ (no wait here)
  auto STAGE_ISSUE = [&](int s_) {
    int gr = (s_ >> 1) * CT + c;
    if (gr >= C_) gr = C_ - 1;
    const float* rp = praw + (size_t)gr * D_ + j * 32;
#pragma unroll
    for (int k = 0; k < 8; ++k) vst[k] = *(const float4*)(rp + k * 4);
  };

  // consume staging regs: col norm (4-thread reduce), scale-fold, swizzled write
  auto CVT_WRITE = [&](int s_, int pp) {
    float ss = 0.f;
#pragma unroll
    for (int k = 0; k < 8; ++k)
      ss += vst[k].x * vst[k].x + vst[k].y * vst[k].y + vst[k].z * vst[k].z + vst[k].w * vst[k].w;
    ss += __shfl_xor(ss, 1);
    ss += __shfl_xor(ss, 2);
    float sc = ((s_ >> 1) * CT + c < C_) ? 3.0f * __frsqrt_rn(fmaxf(ss, 1e-24f)) : 0.0f;
    unsigned char* Bb = bbuf[pp];
#pragma unroll
    for (int i = 0; i < 4; ++i) {
      union { short8 s8; __hip_bfloat162 h[4]; } u;
      u.h[0] = __float22bfloat162_rn(make_float2(vst[2*i].x * sc, vst[2*i].y * sc));
      u.h[1] = __float22bfloat162_rn(make_float2(vst[2*i].z * sc, vst[2*i].w * sc));
      u.h[2] = __float22bfloat162_rn(make_float2(vst[2*i+1].x * sc, vst[2*i+1].y * sc));
      u.h[3] = __float22bfloat162_rn(make_float2(vst[2*i+1].z * sc, vst[2*i+1].w * sc));
      int lu = j * 4 + i;                     // logical 16B unit (dims j*32+i*8..)
      int pu = lu ^ (c & 7);                  // XOR swizzle (R6-proven pair)
      *(short8*)(Bb + (size_t)c * 256 + pu * 16) = u.s8;
    }
  };

  auto COMPUTE = [&](int pp) {
    const unsigned char* Bb = bbuf[pp];
#pragma unroll
    for (int g = 0; g < 8; ++g) {
      const int cg = g * 16 + ll;
      short8 bfr[4];
#pragma unroll
      for (int ks = 0; ks < 4; ++ks)
        bfr[ks] = *(const short8*)(Bb + (size_t)cg * 256 + ((ks * 4 + lq) ^ (cg & 7)) * 16);
      f32x4 acc0 = (f32x4){0.f, 0.f, 0.f, 0.f};
      f32x4 acc1 = (f32x4){0.f, 0.f, 0.f, 0.f};
#pragma unroll
      for (int ks = 0; ks < 4; ++ks) {
        acc0 = __builtin_amdgcn_mfma_f32_16x16x32_bf16(a[0][ks], bfr[ks], acc0, 0, 0, 0);
        acc1 = __builtin_amdgcn_mfma_f32_16x16x32_bf16(a[1][ks], bfr[ks], acc1, 0, 0, 0);
      }
#pragma unroll
      for (int r = 0; r < 4; ++r) {
        part[0][r] += EXP2F(fmaf(acc0[r], K2S, K18S));
        part[1][r] += EXP2F(fmaf(acc1[r], K2S, K18S));
      }
    }
  };

  // prologue: stage + convert step s into bbuf[0]
  STAGE_ISSUE(s);
  CVT_WRITE(s, 0);          // compiler inserts the vmcnt wait before first use
  __syncthreads();

  int p = 0;
  while (true) {
    const int sn = s + MAIN_GRID;
    const bool hn = (sn < NSTEP);
    if (hn) {
      STAGE_ISSUE(sn);                        // 8 indep loads take flight
      __builtin_amdgcn_sched_barrier(0);      // pin issue above COMPUTE
    }
    COMPUTE(p);                               // ~2us of MFMA+exp hides HBM
    if (hn) CVT_WRITE(sn, p ^ 1);             // waits loads, fills other buffer
    __syncthreads();                          // ONE barrier per step
    if (!hn) break;
    s = sn;
    p ^= 1;
  }

  // epilogue: 16-lane reduce; pt[block][256 rows of its half]
#pragma unroll
  for (int m = 0; m < 2; ++m)
#pragma unroll
    for (int r = 0; r < 4; ++r) {
      float v = part[m][r];
      v += __shfl_xor(v, 1);
      v += __shfl_xor(v, 2);
      v += __shfl_xor(v, 4);
      v += __shfl_xor(v, 8);
      if (ll == 0)
        pt[(size_t)blockIdx.x * 256 + w * 32 + m * 16 + lq * 4 + r] = v;
    }
}

// --- kernel 2: per-row combine + positive distance + loss ---------------------
__global__ __launch_bounds__(256) void finalize_rows_kernel(
    const float* __restrict__ praw, const float* __restrict__ batch,
    const int* __restrict__ labels, const float* __restrict__ pt,
    float* __restrict__ lossb)
{
  int lane = threadIdx.x & 63, wv = threadIdx.x >> 6;
  int row = blockIdx.x * 4 + wv;             // grid=128 -> 512 rows
  int lab = labels[row];
  float2 pv = *(const float2*)(praw + (size_t)lab * D_ + lane * 2);
  float2 xv = *(const float2*)(batch + (size_t)row * D_ + lane * 2);
  float ssp = pv.x * pv.x + pv.y * pv.y;
  float ssx = xv.x * xv.x + xv.y * xv.y;
  float dp  = xv.x * pv.x + xv.y * pv.y;
#pragma unroll
  for (int off = 32; off; off >>= 1) {
    ssp += __shfl_xor(ssp, off);
    ssx += __shfl_xor(ssx, off);
    dp  += __shfl_xor(dp, off);
  }
  float pd = 18.f - 18.f * dp / (fmaxf(sqrtf(ssx), 1e-12f) * fmaxf(sqrtf(ssp), 1e-12f));
  // blocks with (b & 1) == (row>>8) cover this row; 256 of them
  const int hr = row >> 8;
  const int lr = row & 255;
  float sum = 0.f;
  for (int k = lane; k < 256; k += 64)
    sum += pt[(size_t)(hr + 2 * k) * 256 + lr];
#pragma unroll
  for (int off = 32; off; off >>= 1) sum += __shfl_xor(sum, off);
  if (lane == 0) {
    const float tail = (float)NPAD * EXP2F(K18S);   // zero-col contributions
    lossb[row] = pd + logf(sum - __expf(-pd) - tail);
  }
}

// --- kernel 3: mean over 512 rows ---------------------------------------------
__global__ __launch_bounds__(512) void reduce_mean_kernel(
    const float* __restrict__ lossb, float* __restrict__ out)
{
  int t = threadIdx.x;
  float v = lossb[t];
#pragma unroll
  for (int off = 1; off < 64; off <<= 1) v += __shfl_xor(v, off);
  __shared__ float red[8];
  if ((t & 63) == 0) red[t >> 6] = v;
  __syncthreads();
  if (t == 0) {
    float tot = 0.f;
    for (int i = 0; i < 8; ++i) tot += red[i];
    out[0] = tot / (float)B_;
  }
}

extern "C" void kernel_launch(void* const* d_in, const int* in_sizes, int n_in,
                              void* d_out, int out_size, void* d_ws, size_t ws_size,
                              hipStream_t stream)
{
  const float* batch   = (const float*)d_in[0];
  const int*   labels  = (const int*)d_in[1];
  const float* proxies = (const float*)d_in[2];
  float* out = (float*)d_out;

  unsigned char* ws = (unsigned char*)d_ws;
  float* pt    = (float*)ws;                                  // 512*256*4 = 512 KB
  float* lossb = (float*)(ws + (size_t)MAIN_GRID * 256 * 4);  // 2 KB

  pnca_main_kernel<<<MAIN_GRID, 512, 0, stream>>>(proxies, batch, pt);
  finalize_rows_kernel<<<B_ / 4, 256, 0, stream>>>(proxies, batch, labels, pt, lossb);
  reduce_mean_kernel<<<1, 512, 0, stream>>>(lossb, out);
}